// Round 1
// baseline (2890.867 us; speedup 1.0000x reference)
//
#include <hip/hip_runtime.h>

// ---------------------------------------------------------------------------
// 4-layer GCN, all-f32.
// Per call: degree -> dis=rsqrt(deg+1) -> CSR by dst (hist, scan, fill) ->
// 4x [GEMM (no bias), aggregate(+bias,+leaky)] -> softmax fused in last agg.
// ---------------------------------------------------------------------------

#define NEG_SLOPE 0.01f

__global__ void k_degree(const int* __restrict__ dst, int* __restrict__ cnt, int E) {
    int i = blockIdx.x * 256 + threadIdx.x;
    if (i < E) atomicAdd(&cnt[dst[i]], 1);
}

__global__ void k_dis(const int* __restrict__ cnt, float* __restrict__ dis, int N) {
    int i = blockIdx.x * 256 + threadIdx.x;
    if (i < N) dis[i] = rsqrtf((float)cnt[i] + 1.0f);
}

// scan 1: per-1024-chunk exclusive scan (into row_ptr), chunk totals to partials
__global__ void k_scan1(const int* __restrict__ cnt, int* __restrict__ excl,
                        int* __restrict__ partials, int n) {
    __shared__ int tmp[1024];
    int tid = threadIdx.x;
    int i = blockIdx.x * 1024 + tid;
    int v = (i < n) ? cnt[i] : 0;
    tmp[tid] = v;
    __syncthreads();
    for (int off = 1; off < 1024; off <<= 1) {
        int t = (tid >= off) ? tmp[tid - off] : 0;
        __syncthreads();
        tmp[tid] += t;
        __syncthreads();
    }
    if (i < n) excl[i] = tmp[tid] - v;
    if (tid == 1023) partials[blockIdx.x] = tmp[tid];
}

// scan 2: single-block exclusive scan of chunk totals (nchunks <= 1024)
__global__ void k_scan2(int* __restrict__ partials, int n) {
    __shared__ int tmp[1024];
    int tid = threadIdx.x;
    int v = (tid < n) ? partials[tid] : 0;
    tmp[tid] = v;
    __syncthreads();
    for (int off = 1; off < 1024; off <<= 1) {
        int t = (tid >= off) ? tmp[tid - off] : 0;
        __syncthreads();
        tmp[tid] += t;
        __syncthreads();
    }
    if (tid < n) partials[tid] = tmp[tid] - v;
}

// scan 3: add chunk offsets; init fill cursors; row_ptr[N]=E
__global__ void k_scan3(int* __restrict__ row_ptr, const int* __restrict__ partials,
                        int* __restrict__ fill_ptr, int n, int E) {
    int i = blockIdx.x * 256 + threadIdx.x;
    if (i < n) {
        int v = row_ptr[i] + partials[i >> 10];
        row_ptr[i] = v;
        fill_ptr[i] = v;
    }
    if (i == n) row_ptr[n] = E;
}

// fill CSR: per edge, slot under dst; store (src, dis[src]) as int2
__global__ void k_fill(const int* __restrict__ src, const int* __restrict__ dst,
                       const float* __restrict__ dis, int* __restrict__ fill_ptr,
                       int2* __restrict__ csr, int E) {
    int i = blockIdx.x * 256 + threadIdx.x;
    if (i < E) {
        int s = src[i], d = dst[i];
        int p = atomicAdd(&fill_ptr[d], 1);
        csr[p] = make_int2(s, __float_as_int(dis[s]));
    }
}

// ---------------------------------------------------------------------------
// f32 tiled GEMM: C[M,Nf] = A[M,K] @ B[K,Nf].  BM=128, BK=8, BN=128 or 64.
// 256 threads, micro-tile 8 x (BN/16).
// ---------------------------------------------------------------------------
template <int BN>
__global__ __launch_bounds__(256) void k_gemm(const float* __restrict__ A,
                                              const float* __restrict__ B,
                                              float* __restrict__ C,
                                              int M, int K, int Nf) {
    constexpr int BM = 128, BK = 8;
    constexpr int TM = 8, TN = BN / 16;
    __shared__ float As[BK][BM];
    __shared__ float Bs[BK][BN];
    const int tid = threadIdx.x;
    const int tx = tid & 15, ty = tid >> 4;
    const int rowBase = blockIdx.x * BM;
    const int colBase = blockIdx.y * BN;

    const int a_row = tid >> 1;        // 0..127
    const int a_k   = (tid & 1) * 4;   // 0 or 4

    float acc[TM][TN] = {};

    for (int kt = 0; kt < K; kt += BK) {
        // global loads first (latency), then barrier, then LDS writes
        float4 av = make_float4(0.f, 0.f, 0.f, 0.f);
        int ar = rowBase + a_row;
        if (ar < M) av = *(const float4*)&A[(size_t)ar * K + kt + a_k];

        if constexpr (BN == 128) {
            const int b_row = tid >> 5;        // 0..7
            const int b_c   = (tid & 31) * 4;  // 0..124
            float4 bv = *(const float4*)&B[(size_t)(kt + b_row) * Nf + colBase + b_c];
            __syncthreads();
            As[a_k + 0][a_row] = av.x; As[a_k + 1][a_row] = av.y;
            As[a_k + 2][a_row] = av.z; As[a_k + 3][a_row] = av.w;
            *(float4*)&Bs[b_row][b_c] = bv;
        } else {
            const int b_row = tid >> 5;        // 0..7
            const int b_c   = (tid & 31) * 2;  // 0..62
            float2 bv = *(const float2*)&B[(size_t)(kt + b_row) * Nf + colBase + b_c];
            __syncthreads();
            As[a_k + 0][a_row] = av.x; As[a_k + 1][a_row] = av.y;
            As[a_k + 2][a_row] = av.z; As[a_k + 3][a_row] = av.w;
            *(float2*)&Bs[b_row][b_c] = bv;
        }
        __syncthreads();

#pragma unroll
        for (int k = 0; k < BK; ++k) {
            float a[TM], b[TN];
            *(float4*)&a[0] = *(const float4*)&As[k][ty * TM];
            *(float4*)&a[4] = *(const float4*)&As[k][ty * TM + 4];
            *(float4*)&b[0] = *(const float4*)&Bs[k][tx * TN];
            if constexpr (TN == 8) *(float4*)&b[4] = *(const float4*)&Bs[k][tx * TN + 4];
#pragma unroll
            for (int i = 0; i < TM; ++i)
#pragma unroll
                for (int j = 0; j < TN; ++j)
                    acc[i][j] = fmaf(a[i], b[j], acc[i][j]);
        }
    }

#pragma unroll
    for (int i = 0; i < TM; ++i) {
        int r = rowBase + ty * TM + i;
        if (r < M) {
            float* cp = &C[(size_t)r * Nf + colBase + tx * TN];
            *(float4*)cp = make_float4(acc[i][0], acc[i][1], acc[i][2], acc[i][3]);
            if constexpr (TN == 8)
                *(float4*)(cp + 4) = make_float4(acc[i][4], acc[i][5], acc[i][6], acc[i][7]);
        }
    }
}

// ---------------------------------------------------------------------------
// Aggregate F=256: one wave per node, lane holds float4 (64*4 = 256 feats).
// out[i] = leaky( dis_i * sum_e w_e*H[src_e] + dis_i^2 * H[i] + b )
// ---------------------------------------------------------------------------
__global__ __launch_bounds__(256) void k_agg256(const float4* __restrict__ H,
                                                const int* __restrict__ row_ptr,
                                                const int2* __restrict__ csr,
                                                const float* __restrict__ dis,
                                                const float* __restrict__ bias,
                                                float4* __restrict__ out, int N) {
    int wave = threadIdx.x >> 6;
    int lane = threadIdx.x & 63;
    int node = blockIdx.x * 4 + wave;
    if (node >= N) return;
    int beg = row_ptr[node], end = row_ptr[node + 1];
    float ax = 0.f, ay = 0.f, az = 0.f, aw = 0.f;
    for (int e = beg; e < end; ++e) {
        int2 sw = csr[e];
        float w = __int_as_float(sw.y);
        float4 v = H[(size_t)sw.x * 64 + lane];
        ax = fmaf(w, v.x, ax);
        ay = fmaf(w, v.y, ay);
        az = fmaf(w, v.z, az);
        aw = fmaf(w, v.w, aw);
    }
    float di = dis[node];
    float d2 = di * di;
    float4 sv = H[(size_t)node * 64 + lane];
    float4 b  = ((const float4*)bias)[lane];
    float rx = fmaf(di, ax, fmaf(d2, sv.x, b.x));
    float ry = fmaf(di, ay, fmaf(d2, sv.y, b.y));
    float rz = fmaf(di, az, fmaf(d2, sv.z, b.z));
    float rw = fmaf(di, aw, fmaf(d2, sv.w, b.w));
    rx = rx > 0.f ? rx : NEG_SLOPE * rx;
    ry = ry > 0.f ? ry : NEG_SLOPE * ry;
    rz = rz > 0.f ? rz : NEG_SLOPE * rz;
    rw = rw > 0.f ? rw : NEG_SLOPE * rw;
    out[(size_t)node * 64 + lane] = make_float4(rx, ry, rz, rw);
}

// ---------------------------------------------------------------------------
// Aggregate F=64 + softmax: one wave per node, lane = class.
// ---------------------------------------------------------------------------
__global__ __launch_bounds__(256) void k_agg64_softmax(const float* __restrict__ H,
                                                       const int* __restrict__ row_ptr,
                                                       const int2* __restrict__ csr,
                                                       const float* __restrict__ dis,
                                                       const float* __restrict__ bias,
                                                       float* __restrict__ out, int N) {
    int wave = threadIdx.x >> 6;
    int lane = threadIdx.x & 63;
    int node = blockIdx.x * 4 + wave;
    if (node >= N) return;
    int beg = row_ptr[node], end = row_ptr[node + 1];
    float acc = 0.f;
    for (int e = beg; e < end; ++e) {
        int2 sw = csr[e];
        acc = fmaf(__int_as_float(sw.y), H[(size_t)sw.x * 64 + lane], acc);
    }
    float di = dis[node];
    float v = fmaf(di, acc, fmaf(di * di, H[(size_t)node * 64 + lane], bias[lane]));
    // softmax over 64 lanes
    float m = v;
#pragma unroll
    for (int off = 32; off; off >>= 1) m = fmaxf(m, __shfl_xor(m, off));
    float ex = __expf(v - m);
    float s = ex;
#pragma unroll
    for (int off = 32; off; off >>= 1) s += __shfl_xor(s, off);
    out[(size_t)node * 64 + lane] = ex / s;
}

// ---------------------------------------------------------------------------
extern "C" void kernel_launch(void* const* d_in, const int* in_sizes, int n_in,
                              void* d_out, int out_size, void* d_ws, size_t ws_size,
                              hipStream_t stream) {
    const float* x  = (const float*)d_in[0];
    const int*   ei = (const int*)d_in[1];
    const float* W0 = (const float*)d_in[2];
    const float* b0 = (const float*)d_in[3];
    const float* W1 = (const float*)d_in[4];
    const float* b1 = (const float*)d_in[5];
    const float* W2 = (const float*)d_in[6];
    const float* b2 = (const float*)d_in[7];
    const float* W3 = (const float*)d_in[8];
    const float* b3 = (const float*)d_in[9];

    const int N = in_sizes[0] / 512;   // 100000
    const int E = in_sizes[1] / 2;     // 3200000
    const int* src = ei;
    const int* dst = ei + E;

    // workspace layout (256B aligned slabs)
    auto align256 = [](size_t v) { return (v + 255) & ~(size_t)255; };
    char* w = (char*)d_ws;
    float* hA = (float*)w;           w += align256((size_t)N * 256 * 4);
    float* hB = (float*)w;           w += align256((size_t)N * 256 * 4);
    int2*  csr = (int2*)w;           w += align256((size_t)E * 8);
    int*   cnt = (int*)w;            w += align256((size_t)N * 4);
    float* dis = (float*)w;          w += align256((size_t)N * 4);
    int*   row_ptr = (int*)w;        w += align256((size_t)(N + 1) * 4);
    int*   fill_ptr = (int*)w;       w += align256((size_t)N * 4);
    int*   partials = (int*)w;       w += align256((size_t)1024 * 4);
    (void)ws_size; (void)n_in; (void)out_size;

    const int nchunks = (N + 1023) / 1024;

    hipMemsetAsync(cnt, 0, (size_t)N * 4, stream);
    k_degree<<<(E + 255) / 256, 256, 0, stream>>>(dst, cnt, E);
    k_dis<<<(N + 255) / 256, 256, 0, stream>>>(cnt, dis, N);
    k_scan1<<<nchunks, 1024, 0, stream>>>(cnt, row_ptr, partials, N);
    k_scan2<<<1, 1024, 0, stream>>>(partials, nchunks);
    k_scan3<<<(N + 1 + 255) / 256, 256, 0, stream>>>(row_ptr, partials, fill_ptr, N, E);
    k_fill<<<(E + 255) / 256, 256, 0, stream>>>(src, dst, dis, fill_ptr, csr, E);

    const int gridM = (N + 127) / 128;
    const int nodeBlocks = (N + 3) / 4;

    // layer 0: x[N,512] @ W0[512,256] -> hA; agg -> hB (leaky)
    k_gemm<128><<<dim3(gridM, 2), 256, 0, stream>>>(x, W0, hA, N, 512, 256);
    k_agg256<<<nodeBlocks, 256, 0, stream>>>((const float4*)hA, row_ptr, csr, dis, b0,
                                             (float4*)hB, N);
    // layer 1
    k_gemm<128><<<dim3(gridM, 2), 256, 0, stream>>>(hB, W1, hA, N, 256, 256);
    k_agg256<<<nodeBlocks, 256, 0, stream>>>((const float4*)hA, row_ptr, csr, dis, b1,
                                             (float4*)hB, N);
    // layer 2
    k_gemm<128><<<dim3(gridM, 2), 256, 0, stream>>>(hB, W2, hA, N, 256, 256);
    k_agg256<<<nodeBlocks, 256, 0, stream>>>((const float4*)hA, row_ptr, csr, dis, b2,
                                             (float4*)hB, N);
    // layer 3: hB[N,256] @ W3[256,64] -> hA (N x 64); agg + softmax -> d_out
    k_gemm<64><<<dim3(gridM, 1), 256, 0, stream>>>(hB, W3, hA, N, 256, 64);
    k_agg64_softmax<<<nodeBlocks, 256, 0, stream>>>(hA, row_ptr, csr, dis, b3,
                                                    (float*)d_out, N);
}

// Round 2
// 2876.393 us; speedup vs baseline: 1.0050x; 1.0050x over previous
//
#include <hip/hip_runtime.h>

// ---------------------------------------------------------------------------
// 4-layer GCN, all-f32.
// Per call: degree -> dis=rsqrt(deg+1) -> CSR by dst (hist, scan, fill) ->
// 4x [GEMM (row-prescaled by dis, no bias), aggregate(+bias,+leaky)]
// -> softmax fused in last agg.
// GEMM output H' = dis[row] * (A@W)  so agg needs only src indices:
//   out = leaky( dis_i * (sum_e H'[src_e] + H'[i]) + b )
// Aggregation batches 8 edges per iteration for 8 outstanding gathers/wave.
// ---------------------------------------------------------------------------

#define NEG_SLOPE 0.01f

__global__ void k_degree(const int* __restrict__ dst, int* __restrict__ cnt, int E) {
    int i = blockIdx.x * 256 + threadIdx.x;
    if (i < E) atomicAdd(&cnt[dst[i]], 1);
}

__global__ void k_dis(const int* __restrict__ cnt, float* __restrict__ dis, int N) {
    int i = blockIdx.x * 256 + threadIdx.x;
    if (i < N) dis[i] = rsqrtf((float)cnt[i] + 1.0f);
}

// scan 1: per-1024-chunk exclusive scan (into row_ptr), chunk totals to partials
__global__ void k_scan1(const int* __restrict__ cnt, int* __restrict__ excl,
                        int* __restrict__ partials, int n) {
    __shared__ int tmp[1024];
    int tid = threadIdx.x;
    int i = blockIdx.x * 1024 + tid;
    int v = (i < n) ? cnt[i] : 0;
    tmp[tid] = v;
    __syncthreads();
    for (int off = 1; off < 1024; off <<= 1) {
        int t = (tid >= off) ? tmp[tid - off] : 0;
        __syncthreads();
        tmp[tid] += t;
        __syncthreads();
    }
    if (i < n) excl[i] = tmp[tid] - v;
    if (tid == 1023) partials[blockIdx.x] = tmp[tid];
}

// scan 2: single-block exclusive scan of chunk totals (nchunks <= 1024)
__global__ void k_scan2(int* __restrict__ partials, int n) {
    __shared__ int tmp[1024];
    int tid = threadIdx.x;
    int v = (tid < n) ? partials[tid] : 0;
    tmp[tid] = v;
    __syncthreads();
    for (int off = 1; off < 1024; off <<= 1) {
        int t = (tid >= off) ? tmp[tid - off] : 0;
        __syncthreads();
        tmp[tid] += t;
        __syncthreads();
    }
    if (tid < n) partials[tid] = tmp[tid] - v;
}

// scan 3: add chunk offsets; init fill cursors; row_ptr[N]=E
__global__ void k_scan3(int* __restrict__ row_ptr, const int* __restrict__ partials,
                        int* __restrict__ fill_ptr, int n, int E) {
    int i = blockIdx.x * 256 + threadIdx.x;
    if (i < n) {
        int v = row_ptr[i] + partials[i >> 10];
        row_ptr[i] = v;
        fill_ptr[i] = v;
    }
    if (i == n) row_ptr[n] = E;
}

// fill CSR: per edge, slot under dst; store src index only
__global__ void k_fill(const int* __restrict__ src, const int* __restrict__ dst,
                       int* __restrict__ fill_ptr, int* __restrict__ csr, int E) {
    int i = blockIdx.x * 256 + threadIdx.x;
    if (i < E) {
        int s = src[i], d = dst[i];
        int p = atomicAdd(&fill_ptr[d], 1);
        csr[p] = s;
    }
}

// ---------------------------------------------------------------------------
// f32 tiled GEMM: C[M,Nf] = rowscale[r] * (A[M,K] @ B[K,Nf]).
// BM=128, BK=8, BN=128 or 64. 256 threads, micro-tile 8 x (BN/16).
// ---------------------------------------------------------------------------
template <int BN>
__global__ __launch_bounds__(256) void k_gemm(const float* __restrict__ A,
                                              const float* __restrict__ B,
                                              float* __restrict__ C,
                                              const float* __restrict__ rowscale,
                                              int M, int K, int Nf) {
    constexpr int BM = 128, BK = 8;
    constexpr int TM = 8, TN = BN / 16;
    __shared__ float As[BK][BM];
    __shared__ float Bs[BK][BN];
    const int tid = threadIdx.x;
    const int tx = tid & 15, ty = tid >> 4;
    const int rowBase = blockIdx.x * BM;
    const int colBase = blockIdx.y * BN;

    const int a_row = tid >> 1;        // 0..127
    const int a_k   = (tid & 1) * 4;   // 0 or 4

    float acc[TM][TN] = {};

    for (int kt = 0; kt < K; kt += BK) {
        float4 av = make_float4(0.f, 0.f, 0.f, 0.f);
        int ar = rowBase + a_row;
        if (ar < M) av = *(const float4*)&A[(size_t)ar * K + kt + a_k];

        if constexpr (BN == 128) {
            const int b_row = tid >> 5;        // 0..7
            const int b_c   = (tid & 31) * 4;  // 0..124
            float4 bv = *(const float4*)&B[(size_t)(kt + b_row) * Nf + colBase + b_c];
            __syncthreads();
            As[a_k + 0][a_row] = av.x; As[a_k + 1][a_row] = av.y;
            As[a_k + 2][a_row] = av.z; As[a_k + 3][a_row] = av.w;
            *(float4*)&Bs[b_row][b_c] = bv;
        } else {
            const int b_row = tid >> 5;        // 0..7
            const int b_c   = (tid & 31) * 2;  // 0..62
            float2 bv = *(const float2*)&B[(size_t)(kt + b_row) * Nf + colBase + b_c];
            __syncthreads();
            As[a_k + 0][a_row] = av.x; As[a_k + 1][a_row] = av.y;
            As[a_k + 2][a_row] = av.z; As[a_k + 3][a_row] = av.w;
            *(float2*)&Bs[b_row][b_c] = bv;
        }
        __syncthreads();

#pragma unroll
        for (int k = 0; k < BK; ++k) {
            float a[TM], b[TN];
            *(float4*)&a[0] = *(const float4*)&As[k][ty * TM];
            *(float4*)&a[4] = *(const float4*)&As[k][ty * TM + 4];
            *(float4*)&b[0] = *(const float4*)&Bs[k][tx * TN];
            if constexpr (TN == 8) *(float4*)&b[4] = *(const float4*)&Bs[k][tx * TN + 4];
#pragma unroll
            for (int i = 0; i < TM; ++i)
#pragma unroll
                for (int j = 0; j < TN; ++j)
                    acc[i][j] = fmaf(a[i], b[j], acc[i][j]);
        }
    }

#pragma unroll
    for (int i = 0; i < TM; ++i) {
        int r = rowBase + ty * TM + i;
        if (r < M) {
            float rs = rowscale[r];
            float* cp = &C[(size_t)r * Nf + colBase + tx * TN];
            *(float4*)cp = make_float4(rs * acc[i][0], rs * acc[i][1],
                                       rs * acc[i][2], rs * acc[i][3]);
            if constexpr (TN == 8)
                *(float4*)(cp + 4) = make_float4(rs * acc[i][4], rs * acc[i][5],
                                                 rs * acc[i][6], rs * acc[i][7]);
        }
    }
}

// ---------------------------------------------------------------------------
// Aggregate F=256: one wave per node, lane holds float4 (64*4 = 256 feats).
// H is pre-scaled by dis[row].  8 edges batched per iteration -> 8
// independent gathers in flight per wave.
// out[i] = leaky( dis_i * (sum_e H[src_e] + H[i]) + b )
// ---------------------------------------------------------------------------
__global__ __launch_bounds__(256, 8) void k_agg256(const float4* __restrict__ H,
                                                   const int* __restrict__ row_ptr,
                                                   const int* __restrict__ csr,
                                                   const float* __restrict__ dis,
                                                   const float* __restrict__ bias,
                                                   float4* __restrict__ out, int N) {
    int wave = threadIdx.x >> 6;
    int lane = threadIdx.x & 63;
    int node = blockIdx.x * 4 + wave;
    if (node >= N) return;
    int beg = row_ptr[node], end = row_ptr[node + 1];
    float ax = 0.f, ay = 0.f, az = 0.f, aw = 0.f;

    int e = beg;
    // hot loop: full batches of 8
    for (; e + 8 <= end; e += 8) {
        int msrc = csr[e + (lane & 7)];
#pragma unroll
        for (int j = 0; j < 8; ++j) {
            int s = __shfl(msrc, j);
            float4 v = H[(size_t)s * 64 + lane];
            ax += v.x; ay += v.y; az += v.z; aw += v.w;
        }
    }
    // tail (< 8 edges)
    if (e < end) {
        int idx = e + (lane & 7);
        int msrc = csr[idx < end ? idx : end - 1];
        int n = end - e;
#pragma unroll
        for (int j = 0; j < 8; ++j) {
            if (j < n) {
                int s = __shfl(msrc, j);
                float4 v = H[(size_t)s * 64 + lane];
                ax += v.x; ay += v.y; az += v.z; aw += v.w;
            }
        }
    }

    float di = dis[node];
    float4 sv = H[(size_t)node * 64 + lane];
    float4 b  = ((const float4*)bias)[lane];
    float rx = fmaf(di, ax + sv.x, b.x);
    float ry = fmaf(di, ay + sv.y, b.y);
    float rz = fmaf(di, az + sv.z, b.z);
    float rw = fmaf(di, aw + sv.w, b.w);
    rx = rx > 0.f ? rx : NEG_SLOPE * rx;
    ry = ry > 0.f ? ry : NEG_SLOPE * ry;
    rz = rz > 0.f ? rz : NEG_SLOPE * rz;
    rw = rw > 0.f ? rw : NEG_SLOPE * rw;
    out[(size_t)node * 64 + lane] = make_float4(rx, ry, rz, rw);
}

// ---------------------------------------------------------------------------
// Aggregate F=64 + softmax: one wave per node, lane = class. H pre-scaled.
// ---------------------------------------------------------------------------
__global__ __launch_bounds__(256, 8) void k_agg64_softmax(const float* __restrict__ H,
                                                          const int* __restrict__ row_ptr,
                                                          const int* __restrict__ csr,
                                                          const float* __restrict__ dis,
                                                          const float* __restrict__ bias,
                                                          float* __restrict__ out, int N) {
    int wave = threadIdx.x >> 6;
    int lane = threadIdx.x & 63;
    int node = blockIdx.x * 4 + wave;
    if (node >= N) return;
    int beg = row_ptr[node], end = row_ptr[node + 1];
    float acc = 0.f;

    int e = beg;
    for (; e + 8 <= end; e += 8) {
        int msrc = csr[e + (lane & 7)];
#pragma unroll
        for (int j = 0; j < 8; ++j) {
            int s = __shfl(msrc, j);
            acc += H[(size_t)s * 64 + lane];
        }
    }
    if (e < end) {
        int idx = e + (lane & 7);
        int msrc = csr[idx < end ? idx : end - 1];
        int n = end - e;
#pragma unroll
        for (int j = 0; j < 8; ++j) {
            if (j < n) {
                int s = __shfl(msrc, j);
                acc += H[(size_t)s * 64 + lane];
            }
        }
    }

    float di = dis[node];
    float v = fmaf(di, acc + H[(size_t)node * 64 + lane], bias[lane]);
    // softmax over 64 lanes
    float m = v;
#pragma unroll
    for (int off = 32; off; off >>= 1) m = fmaxf(m, __shfl_xor(m, off));
    float ex = __expf(v - m);
    float s = ex;
#pragma unroll
    for (int off = 32; off; off >>= 1) s += __shfl_xor(s, off);
    out[(size_t)node * 64 + lane] = ex / s;
}

// ---------------------------------------------------------------------------
extern "C" void kernel_launch(void* const* d_in, const int* in_sizes, int n_in,
                              void* d_out, int out_size, void* d_ws, size_t ws_size,
                              hipStream_t stream) {
    const float* x  = (const float*)d_in[0];
    const int*   ei = (const int*)d_in[1];
    const float* W0 = (const float*)d_in[2];
    const float* b0 = (const float*)d_in[3];
    const float* W1 = (const float*)d_in[4];
    const float* b1 = (const float*)d_in[5];
    const float* W2 = (const float*)d_in[6];
    const float* b2 = (const float*)d_in[7];
    const float* W3 = (const float*)d_in[8];
    const float* b3 = (const float*)d_in[9];

    const int N = in_sizes[0] / 512;   // 100000
    const int E = in_sizes[1] / 2;     // 3200000
    const int* src = ei;
    const int* dst = ei + E;

    // workspace layout (256B aligned slabs)
    auto align256 = [](size_t v) { return (v + 255) & ~(size_t)255; };
    char* w = (char*)d_ws;
    float* hA = (float*)w;           w += align256((size_t)N * 256 * 4);
    float* hB = (float*)w;           w += align256((size_t)N * 256 * 4);
    int*   csr = (int*)w;            w += align256((size_t)E * 4);
    int*   cnt = (int*)w;            w += align256((size_t)N * 4);
    float* dis = (float*)w;          w += align256((size_t)N * 4);
    int*   row_ptr = (int*)w;        w += align256((size_t)(N + 1) * 4);
    int*   fill_ptr = (int*)w;       w += align256((size_t)N * 4);
    int*   partials = (int*)w;       w += align256((size_t)1024 * 4);
    (void)ws_size; (void)n_in; (void)out_size;

    const int nchunks = (N + 1023) / 1024;

    hipMemsetAsync(cnt, 0, (size_t)N * 4, stream);
    k_degree<<<(E + 255) / 256, 256, 0, stream>>>(dst, cnt, E);
    k_dis<<<(N + 255) / 256, 256, 0, stream>>>(cnt, dis, N);
    k_scan1<<<nchunks, 1024, 0, stream>>>(cnt, row_ptr, partials, N);
    k_scan2<<<1, 1024, 0, stream>>>(partials, nchunks);
    k_scan3<<<(N + 1 + 255) / 256, 256, 0, stream>>>(row_ptr, partials, fill_ptr, N, E);
    k_fill<<<(E + 255) / 256, 256, 0, stream>>>(src, dst, fill_ptr, csr, E);

    const int gridM = (N + 127) / 128;
    const int nodeBlocks = (N + 3) / 4;

    // layer 0: x[N,512] @ W0 -> hA (row-prescaled); agg -> hB (leaky)
    k_gemm<128><<<dim3(gridM, 2), 256, 0, stream>>>(x, W0, hA, dis, N, 512, 256);
    k_agg256<<<nodeBlocks, 256, 0, stream>>>((const float4*)hA, row_ptr, csr, dis, b0,
                                             (float4*)hB, N);
    // layer 1
    k_gemm<128><<<dim3(gridM, 2), 256, 0, stream>>>(hB, W1, hA, dis, N, 256, 256);
    k_agg256<<<nodeBlocks, 256, 0, stream>>>((const float4*)hA, row_ptr, csr, dis, b1,
                                             (float4*)hB, N);
    // layer 2
    k_gemm<128><<<dim3(gridM, 2), 256, 0, stream>>>(hB, W2, hA, dis, N, 256, 256);
    k_agg256<<<nodeBlocks, 256, 0, stream>>>((const float4*)hA, row_ptr, csr, dis, b2,
                                             (float4*)hB, N);
    // layer 3: hB[N,256] @ W3 -> hA (N x 64, prescaled); agg + softmax -> d_out
    k_gemm<64><<<dim3(gridM, 1), 256, 0, stream>>>(hB, W3, hA, dis, N, 256, 64);
    k_agg64_softmax<<<nodeBlocks, 256, 0, stream>>>(hA, row_ptr, csr, dis, b3,
                                                    (float*)d_out, N);
}

// Round 4
// 2158.976 us; speedup vs baseline: 1.3390x; 1.3323x over previous
//
#include <hip/hip_runtime.h>
#include <hip/hip_fp16.h>

// ---------------------------------------------------------------------------
// 4-layer GCN.
// Per call: degree -> dis=rsqrt(deg+1) -> CSR by dst (hist, scan, fill) ->
// 4x [GEMM (row-prescaled by dis), aggregate(+bias,+leaky)] -> softmax in last.
// GEMM output H' = dis[row] * (A@W); agg: out = leaky(dis_i*(sum H'[src]+H'[i])+b)
// Layers 0-2: H' stored fp16 (halves the random-gather bytes on the capped
// L2-miss path; accumulation stays f32).  Layer 3 H' stays f32 (precision).
// ---------------------------------------------------------------------------

#define NEG_SLOPE 0.01f

__global__ void k_degree(const int* __restrict__ dst, int* __restrict__ cnt, int E) {
    int i = blockIdx.x * 256 + threadIdx.x;
    if (i < E) atomicAdd(&cnt[dst[i]], 1);
}

__global__ void k_dis(const int* __restrict__ cnt, float* __restrict__ dis, int N) {
    int i = blockIdx.x * 256 + threadIdx.x;
    if (i < N) dis[i] = rsqrtf((float)cnt[i] + 1.0f);
}

__global__ void k_scan1(const int* __restrict__ cnt, int* __restrict__ excl,
                        int* __restrict__ partials, int n) {
    __shared__ int tmp[1024];
    int tid = threadIdx.x;
    int i = blockIdx.x * 1024 + tid;
    int v = (i < n) ? cnt[i] : 0;
    tmp[tid] = v;
    __syncthreads();
    for (int off = 1; off < 1024; off <<= 1) {
        int t = (tid >= off) ? tmp[tid - off] : 0;
        __syncthreads();
        tmp[tid] += t;
        __syncthreads();
    }
    if (i < n) excl[i] = tmp[tid] - v;
    if (tid == 1023) partials[blockIdx.x] = tmp[tid];
}

__global__ void k_scan2(int* __restrict__ partials, int n) {
    __shared__ int tmp[1024];
    int tid = threadIdx.x;
    int v = (tid < n) ? partials[tid] : 0;
    tmp[tid] = v;
    __syncthreads();
    for (int off = 1; off < 1024; off <<= 1) {
        int t = (tid >= off) ? tmp[tid - off] : 0;
        __syncthreads();
        tmp[tid] += t;
        __syncthreads();
    }
    if (tid < n) partials[tid] = tmp[tid] - v;
}

__global__ void k_scan3(int* __restrict__ row_ptr, const int* __restrict__ partials,
                        int* __restrict__ fill_ptr, int n, int E) {
    int i = blockIdx.x * 256 + threadIdx.x;
    if (i < n) {
        int v = row_ptr[i] + partials[i >> 10];
        row_ptr[i] = v;
        fill_ptr[i] = v;
    }
    if (i == n) row_ptr[n] = E;
}

__global__ void k_fill(const int* __restrict__ src, const int* __restrict__ dst,
                       int* __restrict__ fill_ptr, int* __restrict__ csr, int E) {
    int i = blockIdx.x * 256 + threadIdx.x;
    if (i < E) {
        int s = src[i], d = dst[i];
        int p = atomicAdd(&fill_ptr[d], 1);
        csr[p] = s;
    }
}

// ---------------------------------------------------------------------------
// f32 tiled GEMM: C[M,Nf] = rowscale[r] * (A[M,K] @ B[K,Nf]).
// BM=128, BK=8, BN=128 or 64. 256 threads, micro-tile 8 x (BN/16).
// HALF_OUT: store C as fp16 (RN).
// ---------------------------------------------------------------------------
template <int BN, bool HALF_OUT>
__global__ __launch_bounds__(256) void k_gemm(const float* __restrict__ A,
                                              const float* __restrict__ B,
                                              float* __restrict__ C,
                                              const float* __restrict__ rowscale,
                                              int M, int K, int Nf) {
    constexpr int BM = 128, BK = 8;
    constexpr int TM = 8, TN = BN / 16;
    __shared__ float As[BK][BM];
    __shared__ float Bs[BK][BN];
    const int tid = threadIdx.x;
    const int tx = tid & 15, ty = tid >> 4;
    const int rowBase = blockIdx.x * BM;
    const int colBase = blockIdx.y * BN;

    const int a_row = tid >> 1;        // 0..127
    const int a_k   = (tid & 1) * 4;   // 0 or 4

    float acc[TM][TN] = {};

    for (int kt = 0; kt < K; kt += BK) {
        float4 av = make_float4(0.f, 0.f, 0.f, 0.f);
        int ar = rowBase + a_row;
        if (ar < M) av = *(const float4*)&A[(size_t)ar * K + kt + a_k];

        if constexpr (BN == 128) {
            const int b_row = tid >> 5;        // 0..7
            const int b_c   = (tid & 31) * 4;  // 0..124
            float4 bv = *(const float4*)&B[(size_t)(kt + b_row) * Nf + colBase + b_c];
            __syncthreads();
            As[a_k + 0][a_row] = av.x; As[a_k + 1][a_row] = av.y;
            As[a_k + 2][a_row] = av.z; As[a_k + 3][a_row] = av.w;
            *(float4*)&Bs[b_row][b_c] = bv;
        } else {
            const int b_row = tid >> 5;        // 0..7
            const int b_c   = (tid & 31) * 2;  // 0..62
            float2 bv = *(const float2*)&B[(size_t)(kt + b_row) * Nf + colBase + b_c];
            __syncthreads();
            As[a_k + 0][a_row] = av.x; As[a_k + 1][a_row] = av.y;
            As[a_k + 2][a_row] = av.z; As[a_k + 3][a_row] = av.w;
            *(float2*)&Bs[b_row][b_c] = bv;
        }
        __syncthreads();

#pragma unroll
        for (int k = 0; k < BK; ++k) {
            float a[TM], b[TN];
            *(float4*)&a[0] = *(const float4*)&As[k][ty * TM];
            *(float4*)&a[4] = *(const float4*)&As[k][ty * TM + 4];
            *(float4*)&b[0] = *(const float4*)&Bs[k][tx * TN];
            if constexpr (TN == 8) *(float4*)&b[4] = *(const float4*)&Bs[k][tx * TN + 4];
#pragma unroll
            for (int i = 0; i < TM; ++i)
#pragma unroll
                for (int j = 0; j < TN; ++j)
                    acc[i][j] = fmaf(a[i], b[j], acc[i][j]);
        }
    }

#pragma unroll
    for (int i = 0; i < TM; ++i) {
        int r = rowBase + ty * TM + i;
        if (r < M) {
            float rs = rowscale[r];
            if constexpr (HALF_OUT) {
                __half hh[TN];
#pragma unroll
                for (int j = 0; j < TN; ++j) hh[j] = __float2half_rn(rs * acc[i][j]);
                __half* cp = (__half*)C + (size_t)r * Nf + colBase + tx * TN;
                if constexpr (TN == 8) *(float4*)cp = *(float4*)hh;
                else                   *(float2*)cp = *(float2*)hh;
            } else {
                float* cp = &C[(size_t)r * Nf + colBase + tx * TN];
                *(float4*)cp = make_float4(rs * acc[i][0], rs * acc[i][1],
                                           rs * acc[i][2], rs * acc[i][3]);
                if constexpr (TN == 8)
                    *(float4*)(cp + 4) = make_float4(rs * acc[i][4], rs * acc[i][5],
                                                     rs * acc[i][6], rs * acc[i][7]);
            }
        }
    }
}

// ---------------------------------------------------------------------------
// Aggregate F=256 from fp16 H' (row = 256 half = 512B; lane reads 8B = float2
// raw = 2x half2).  f32 accumulate; 8 edges batched per iteration.
// out(f32) = leaky( dis_i * (sum_e H'[src_e] + H'[i]) + b )
// ---------------------------------------------------------------------------
__global__ __launch_bounds__(256) void k_agg256_h(const float2* __restrict__ H2,
                                                  const int* __restrict__ row_ptr,
                                                  const int* __restrict__ csr,
                                                  const float* __restrict__ dis,
                                                  const float* __restrict__ bias,
                                                  float4* __restrict__ out, int N) {
    int wave = threadIdx.x >> 6;
    int lane = threadIdx.x & 63;
    int node = blockIdx.x * 4 + wave;
    if (node >= N) return;
    int beg = row_ptr[node], end = row_ptr[node + 1];
    float ax = 0.f, ay = 0.f, az = 0.f, aw = 0.f;

    int e = beg;
    for (; e + 8 <= end; e += 8) {
        int msrc = csr[e + (lane & 7)];
#pragma unroll
        for (int j = 0; j < 8; ++j) {
            int s = __shfl(msrc, j);
            float2 raw = H2[(size_t)s * 64 + lane];
            float2 f0 = __half22float2(*(const __half2*)&raw.x);
            float2 f1 = __half22float2(*(const __half2*)&raw.y);
            ax += f0.x; ay += f0.y; az += f1.x; aw += f1.y;
        }
    }
    if (e < end) {
        int idx = e + (lane & 7);
        int msrc = csr[idx < end ? idx : end - 1];
        int n = end - e;
#pragma unroll
        for (int j = 0; j < 8; ++j) {
            if (j < n) {
                int s = __shfl(msrc, j);
                float2 raw = H2[(size_t)s * 64 + lane];
                float2 f0 = __half22float2(*(const __half2*)&raw.x);
                float2 f1 = __half22float2(*(const __half2*)&raw.y);
                ax += f0.x; ay += f0.y; az += f1.x; aw += f1.y;
            }
        }
    }

    float di = dis[node];
    float2 raws = H2[(size_t)node * 64 + lane];
    float2 s0 = __half22float2(*(const __half2*)&raws.x);
    float2 s1 = __half22float2(*(const __half2*)&raws.y);
    float4 b  = ((const float4*)bias)[lane];
    float rx = fmaf(di, ax + s0.x, b.x);
    float ry = fmaf(di, ay + s0.y, b.y);
    float rz = fmaf(di, az + s1.x, b.z);
    float rw = fmaf(di, aw + s1.y, b.w);
    rx = rx > 0.f ? rx : NEG_SLOPE * rx;
    ry = ry > 0.f ? ry : NEG_SLOPE * ry;
    rz = rz > 0.f ? rz : NEG_SLOPE * rz;
    rw = rw > 0.f ? rw : NEG_SLOPE * rw;
    out[(size_t)node * 64 + lane] = make_float4(rx, ry, rz, rw);
}

// ---------------------------------------------------------------------------
// Aggregate F=64 + softmax: one wave per node, lane = class. H' f32 (precision).
// ---------------------------------------------------------------------------
__global__ __launch_bounds__(256) void k_agg64_softmax(const float* __restrict__ H,
                                                       const int* __restrict__ row_ptr,
                                                       const int* __restrict__ csr,
                                                       const float* __restrict__ dis,
                                                       const float* __restrict__ bias,
                                                       float* __restrict__ out, int N) {
    int wave = threadIdx.x >> 6;
    int lane = threadIdx.x & 63;
    int node = blockIdx.x * 4 + wave;
    if (node >= N) return;
    int beg = row_ptr[node], end = row_ptr[node + 1];
    float acc = 0.f;

    int e = beg;
    for (; e + 8 <= end; e += 8) {
        int msrc = csr[e + (lane & 7)];
#pragma unroll
        for (int j = 0; j < 8; ++j) {
            int s = __shfl(msrc, j);
            acc += H[(size_t)s * 64 + lane];
        }
    }
    if (e < end) {
        int idx = e + (lane & 7);
        int msrc = csr[idx < end ? idx : end - 1];
        int n = end - e;
#pragma unroll
        for (int j = 0; j < 8; ++j) {
            if (j < n) {
                int s = __shfl(msrc, j);
                acc += H[(size_t)s * 64 + lane];
            }
        }
    }

    float di = dis[node];
    float v = fmaf(di, acc + H[(size_t)node * 64 + lane], bias[lane]);
    float m = v;
#pragma unroll
    for (int off = 32; off; off >>= 1) m = fmaxf(m, __shfl_xor(m, off));
    float ex = __expf(v - m);
    float s = ex;
#pragma unroll
    for (int off = 32; off; off >>= 1) s += __shfl_xor(s, off);
    out[(size_t)node * 64 + lane] = ex / s;
}

// ---------------------------------------------------------------------------
extern "C" void kernel_launch(void* const* d_in, const int* in_sizes, int n_in,
                              void* d_out, int out_size, void* d_ws, size_t ws_size,
                              hipStream_t stream) {
    const float* x  = (const float*)d_in[0];
    const int*   ei = (const int*)d_in[1];
    const float* W0 = (const float*)d_in[2];
    const float* b0 = (const float*)d_in[3];
    const float* W1 = (const float*)d_in[4];
    const float* b1 = (const float*)d_in[5];
    const float* W2 = (const float*)d_in[6];
    const float* b2 = (const float*)d_in[7];
    const float* W3 = (const float*)d_in[8];
    const float* b3 = (const float*)d_in[9];

    const int N = in_sizes[0] / 512;   // 100000
    const int E = in_sizes[1] / 2;     // 3200000
    const int* src = ei;
    const int* dst = ei + E;

    auto align256 = [](size_t v) { return (v + 255) & ~(size_t)255; };
    char* w = (char*)d_ws;
    float* hA = (float*)w;           w += align256((size_t)N * 256 * 4);  // fp16 view for L0-2, f32 for L3
    float* hB = (float*)w;           w += align256((size_t)N * 256 * 4);
    int*   csr = (int*)w;            w += align256((size_t)E * 4);
    int*   cnt = (int*)w;            w += align256((size_t)N * 4);
    float* dis = (float*)w;          w += align256((size_t)N * 4);
    int*   row_ptr = (int*)w;        w += align256((size_t)(N + 1) * 4);
    int*   fill_ptr = (int*)w;       w += align256((size_t)N * 4);
    int*   partials = (int*)w;       w += align256((size_t)1024 * 4);
    (void)ws_size; (void)n_in; (void)out_size;

    const int nchunks = (N + 1023) / 1024;

    hipMemsetAsync(cnt, 0, (size_t)N * 4, stream);
    k_degree<<<(E + 255) / 256, 256, 0, stream>>>(dst, cnt, E);
    k_dis<<<(N + 255) / 256, 256, 0, stream>>>(cnt, dis, N);
    k_scan1<<<nchunks, 1024, 0, stream>>>(cnt, row_ptr, partials, N);
    k_scan2<<<1, 1024, 0, stream>>>(partials, nchunks);
    k_scan3<<<(N + 1 + 255) / 256, 256, 0, stream>>>(row_ptr, partials, fill_ptr, N, E);
    k_fill<<<(E + 255) / 256, 256, 0, stream>>>(src, dst, fill_ptr, csr, E);

    const int gridM = (N + 127) / 128;
    const int nodeBlocks = (N + 3) / 4;

    // layers 0-2: GEMM -> fp16 H' ; agg (fp16 gather, f32 out)
    k_gemm<128, true><<<dim3(gridM, 2), 256, 0, stream>>>(x, W0, hA, dis, N, 512, 256);
    k_agg256_h<<<nodeBlocks, 256, 0, stream>>>((const float2*)hA, row_ptr, csr, dis, b0,
                                               (float4*)hB, N);
    k_gemm<128, true><<<dim3(gridM, 2), 256, 0, stream>>>(hB, W1, hA, dis, N, 256, 256);
    k_agg256_h<<<nodeBlocks, 256, 0, stream>>>((const float2*)hA, row_ptr, csr, dis, b1,
                                               (float4*)hB, N);
    k_gemm<128, true><<<dim3(gridM, 2), 256, 0, stream>>>(hB, W2, hA, dis, N, 256, 256);
    k_agg256_h<<<nodeBlocks, 256, 0, stream>>>((const float2*)hA, row_ptr, csr, dis, b2,
                                               (float4*)hB, N);
    // layer 3: f32 throughout (feeds softmax)
    k_gemm<64, false><<<dim3(gridM, 1), 256, 0, stream>>>(hB, W3, hA, dis, N, 256, 64);
    k_agg64_softmax<<<nodeBlocks, 256, 0, stream>>>(hA, row_ptr, csr, dis, b3,
                                                    (float*)d_out, N);
}

// Round 5
// 1611.426 us; speedup vs baseline: 1.7940x; 1.3398x over previous
//
#include <hip/hip_runtime.h>
#include <hip/hip_fp16.h>

// ---------------------------------------------------------------------------
// 4-layer GCN.
// degree -> dis=rsqrt(deg+1) -> CSR by dst -> 4x [MFMA fp16 GEMM (row-
// prescaled by dis, f32 accum), aggregate(+bias,+leaky, fp16 out)] ->
// softmax fused in last agg.
// H' = dis[row]*(A@W) stored fp16 everywhere (absmax floor observed at
// bf16-ulp granularity; fp16 injection provably ~1e-5 at logits).
// ---------------------------------------------------------------------------

#define NEG_SLOPE 0.01f

typedef __attribute__((ext_vector_type(8))) _Float16 f16x8;
typedef __attribute__((ext_vector_type(4))) float f32x4;

__device__ inline f16x8 f16x8_zero() {
    f16x8 v;
#pragma unroll
    for (int q = 0; q < 8; ++q) v[q] = (_Float16)0.f;
    return v;
}

// ------------------------------- setup -------------------------------------
__global__ void k_degree(const int* __restrict__ dst, int* __restrict__ cnt, int E) {
    int i = blockIdx.x * 256 + threadIdx.x;
    if (i < E) atomicAdd(&cnt[dst[i]], 1);
}

__global__ void k_dis(const int* __restrict__ cnt, float* __restrict__ dis, int N) {
    int i = blockIdx.x * 256 + threadIdx.x;
    if (i < N) dis[i] = rsqrtf((float)cnt[i] + 1.0f);
}

__global__ void k_scan1(const int* __restrict__ cnt, int* __restrict__ excl,
                        int* __restrict__ partials, int n) {
    __shared__ int tmp[1024];
    int tid = threadIdx.x;
    int i = blockIdx.x * 1024 + tid;
    int v = (i < n) ? cnt[i] : 0;
    tmp[tid] = v;
    __syncthreads();
    for (int off = 1; off < 1024; off <<= 1) {
        int t = (tid >= off) ? tmp[tid - off] : 0;
        __syncthreads();
        tmp[tid] += t;
        __syncthreads();
    }
    if (i < n) excl[i] = tmp[tid] - v;
    if (tid == 1023) partials[blockIdx.x] = tmp[tid];
}

__global__ void k_scan2(int* __restrict__ partials, int n) {
    __shared__ int tmp[1024];
    int tid = threadIdx.x;
    int v = (tid < n) ? partials[tid] : 0;
    tmp[tid] = v;
    __syncthreads();
    for (int off = 1; off < 1024; off <<= 1) {
        int t = (tid >= off) ? tmp[tid - off] : 0;
        __syncthreads();
        tmp[tid] += t;
        __syncthreads();
    }
    if (tid < n) partials[tid] = tmp[tid] - v;
}

__global__ void k_scan3(int* __restrict__ row_ptr, const int* __restrict__ partials,
                        int* __restrict__ fill_ptr, int n, int E) {
    int i = blockIdx.x * 256 + threadIdx.x;
    if (i < n) {
        int v = row_ptr[i] + partials[i >> 10];
        row_ptr[i] = v;
        fill_ptr[i] = v;
    }
    if (i == n) row_ptr[n] = E;
}

__global__ void k_fill(const int* __restrict__ src, const int* __restrict__ dst,
                       int* __restrict__ fill_ptr, int* __restrict__ csr, int E) {
    int i = blockIdx.x * 256 + threadIdx.x;
    if (i < E) {
        int s = src[i], d = dst[i];
        int p = atomicAdd(&fill_ptr[d], 1);
        csr[p] = s;
    }
}

// W[K][Nf] f32 -> Wt[Nf][K] fp16 (tiny matrices, once per call)
__global__ void k_convW(const float* __restrict__ W, _Float16* __restrict__ Wt,
                        int K, int Nf) {
    int gid = blockIdx.x * 256 + threadIdx.x;
    if (gid < K * Nf) {
        int n = gid / K, k = gid - n * K;
        Wt[gid] = (_Float16)W[(size_t)k * Nf + n];
    }
}

// ---------------------------------------------------------------------------
// MFMA fp16 GEMM: C[M,Nf] = rowscale[r] * (A[M,K] @ Wt^T), Wt is [Nf][K] fp16.
// BM=128, BK=32. 256 threads = 4 waves.
//   BN=128: waves 2x2, each 64x64 (4x4 frags of 16x16x32).
//   BN= 64: waves 4x1, each 32x64 (2x4 frags).
// Frag layouts (m89/m91-verified): A[m=lane&15][k=quad*8+j],
// B[n=lane&15][k=quad*8+j], C[col=lane&15, row=quad*4+reg].
// ---------------------------------------------------------------------------
template <int BN, bool A_HALF, bool OUT_HALF>
__global__ __launch_bounds__(256) void k_gemm_mfma(const void* __restrict__ Ap,
                                                   const _Float16* __restrict__ Bt,
                                                   void* __restrict__ Cp,
                                                   const float* __restrict__ rowscale,
                                                   int M, int K, int Nf) {
    constexpr int BM = 128, BK = 32;
    constexpr int WAVES_N = (BN == 128) ? 2 : 1;
    constexpr int WAVES_M = 4 / WAVES_N;
    constexpr int WM = BM / (WAVES_M * 16);   // 4 (BN=128) / 2 (BN=64)
    constexpr int WN = BN / (WAVES_N * 16);   // 4
    constexpr int LDK = BK + 8;               // pad -> 2-way LDS aliasing (free)
    __shared__ _Float16 As[BM][LDK];
    __shared__ _Float16 Bs[BN][LDK];

    const int tid = threadIdx.x;
    const int ln = tid & 63, wv = tid >> 6;
    const int wm = wv / WAVES_N, wn = wv % WAVES_N;
    const int rowq = wm * WM * 16, colq = wn * WN * 16;
    const int rowBase = blockIdx.x * BM;
    const int colBase = blockIdx.y * BN;
    const int l15 = ln & 15, lq = ln >> 4;

    f32x4 acc[WM][WN];
#pragma unroll
    for (int i = 0; i < WM; ++i)
#pragma unroll
        for (int j = 0; j < WN; ++j) {
            acc[i][j][0] = 0.f; acc[i][j][1] = 0.f;
            acc[i][j][2] = 0.f; acc[i][j][3] = 0.f;
        }

    constexpr int ASL2 = (BM * BK / 8) / 256;   // 2
    constexpr int BSL2 = (BN * BK / 8) / 256;   // 2 or 1

    for (int kt = 0; kt < K; kt += BK) {
        // global loads to regs
        f16x8 aL[ASL2];
        float4 aF[ASL2][2];
#pragma unroll
        for (int s2 = 0; s2 < ASL2; ++s2) {
            int s = tid + s2 * 256;
            int r = s >> 2, k0 = (s & 3) * 8;
            int gr = rowBase + r;
            if constexpr (A_HALF) {
                aL[s2] = (gr < M)
                    ? *(const f16x8*)((const _Float16*)Ap + (size_t)gr * K + kt + k0)
                    : f16x8_zero();
            } else {
                if (gr < M) {
                    const float* ap = (const float*)Ap + (size_t)gr * K + kt + k0;
                    aF[s2][0] = *(const float4*)ap;
                    aF[s2][1] = *(const float4*)(ap + 4);
                } else {
                    aF[s2][0] = make_float4(0.f, 0.f, 0.f, 0.f);
                    aF[s2][1] = make_float4(0.f, 0.f, 0.f, 0.f);
                }
            }
        }
        f16x8 bL[BSL2];
#pragma unroll
        for (int s2 = 0; s2 < BSL2; ++s2) {
            int s = tid + s2 * 256;
            int n = s >> 2, k0 = (s & 3) * 8;
            bL[s2] = *(const f16x8*)&Bt[(size_t)(colBase + n) * K + kt + k0];
        }
        __syncthreads();   // previous iteration's frag reads done
        // LDS writes
#pragma unroll
        for (int s2 = 0; s2 < ASL2; ++s2) {
            int s = tid + s2 * 256;
            int r = s >> 2, k0 = (s & 3) * 8;
            if constexpr (A_HALF) {
                *(f16x8*)&As[r][k0] = aL[s2];
            } else {
                f16x8 h;
                h[0] = (_Float16)aF[s2][0].x; h[1] = (_Float16)aF[s2][0].y;
                h[2] = (_Float16)aF[s2][0].z; h[3] = (_Float16)aF[s2][0].w;
                h[4] = (_Float16)aF[s2][1].x; h[5] = (_Float16)aF[s2][1].y;
                h[6] = (_Float16)aF[s2][1].z; h[7] = (_Float16)aF[s2][1].w;
                *(f16x8*)&As[r][k0] = h;
            }
        }
#pragma unroll
        for (int s2 = 0; s2 < BSL2; ++s2) {
            int s = tid + s2 * 256;
            int n = s >> 2, k0 = (s & 3) * 8;
            *(f16x8*)&Bs[n][k0] = bL[s2];
        }
        __syncthreads();
        // frags + MFMA
        f16x8 af[WM], bf[WN];
#pragma unroll
        for (int i = 0; i < WM; ++i)
            af[i] = *(const f16x8*)&As[rowq + i * 16 + l15][lq * 8];
#pragma unroll
        for (int j = 0; j < WN; ++j)
            bf[j] = *(const f16x8*)&Bs[colq + j * 16 + l15][lq * 8];
#pragma unroll
        for (int i = 0; i < WM; ++i)
#pragma unroll
            for (int j = 0; j < WN; ++j)
                acc[i][j] = __builtin_amdgcn_mfma_f32_16x16x32_f16(af[i], bf[j],
                                                                   acc[i][j], 0, 0, 0);
    }

    // epilogue: C[col=l15, row=lq*4+r] per frag; apply rowscale
#pragma unroll
    for (int i = 0; i < WM; ++i) {
#pragma unroll
        for (int r = 0; r < 4; ++r) {
            int row = rowBase + rowq + i * 16 + lq * 4 + r;
            if (row < M) {
                float rs = rowscale[row];
#pragma unroll
                for (int j = 0; j < WN; ++j) {
                    int col = colBase + colq + j * 16 + l15;
                    float v = rs * acc[i][j][r];
                    if constexpr (OUT_HALF)
                        ((_Float16*)Cp)[(size_t)row * Nf + col] = (_Float16)v;
                    else
                        ((float*)Cp)[(size_t)row * Nf + col] = v;
                }
            }
        }
    }
}

// ---------------------------------------------------------------------------
// Aggregate F=256 from fp16 H' (row = 512B; lane reads 8B). f32 accumulate;
// 8 edges batched. out (fp16) = leaky( dis_i*(sum H'[src] + H'[i]) + b )
// ---------------------------------------------------------------------------
__global__ __launch_bounds__(256) void k_agg256_h(const float2* __restrict__ H2,
                                                  const int* __restrict__ row_ptr,
                                                  const int* __restrict__ csr,
                                                  const float* __restrict__ dis,
                                                  const float* __restrict__ bias,
                                                  _Float16* __restrict__ out, int N) {
    int wave = threadIdx.x >> 6;
    int lane = threadIdx.x & 63;
    int node = blockIdx.x * 4 + wave;
    if (node >= N) return;
    int beg = row_ptr[node], end = row_ptr[node + 1];
    float ax = 0.f, ay = 0.f, az = 0.f, aw = 0.f;

    int e = beg;
    for (; e + 8 <= end; e += 8) {
        int msrc = csr[e + (lane & 7)];
#pragma unroll
        for (int j = 0; j < 8; ++j) {
            int s = __shfl(msrc, j);
            float2 raw = H2[(size_t)s * 64 + lane];
            float2 f0 = __half22float2(*(const __half2*)&raw.x);
            float2 f1 = __half22float2(*(const __half2*)&raw.y);
            ax += f0.x; ay += f0.y; az += f1.x; aw += f1.y;
        }
    }
    if (e < end) {
        int idx = e + (lane & 7);
        int msrc = csr[idx < end ? idx : end - 1];
        int n = end - e;
#pragma unroll
        for (int j = 0; j < 8; ++j) {
            if (j < n) {
                int s = __shfl(msrc, j);
                float2 raw = H2[(size_t)s * 64 + lane];
                float2 f0 = __half22float2(*(const __half2*)&raw.x);
                float2 f1 = __half22float2(*(const __half2*)&raw.y);
                ax += f0.x; ay += f0.y; az += f1.x; aw += f1.y;
            }
        }
    }

    float di = dis[node];
    float2 raws = H2[(size_t)node * 64 + lane];
    float2 s0 = __half22float2(*(const __half2*)&raws.x);
    float2 s1 = __half22float2(*(const __half2*)&raws.y);
    float4 b  = ((const float4*)bias)[lane];
    float rx = fmaf(di, ax + s0.x, b.x);
    float ry = fmaf(di, ay + s0.y, b.y);
    float rz = fmaf(di, az + s1.x, b.z);
    float rw = fmaf(di, aw + s1.y, b.w);
    rx = rx > 0.f ? rx : NEG_SLOPE * rx;
    ry = ry > 0.f ? ry : NEG_SLOPE * ry;
    rz = rz > 0.f ? rz : NEG_SLOPE * rz;
    rw = rw > 0.f ? rw : NEG_SLOPE * rw;
    _Float16 hh[4] = {(_Float16)rx, (_Float16)ry, (_Float16)rz, (_Float16)rw};
    *(float2*)&out[(size_t)node * 256 + lane * 4] = *(float2*)hh;
}

// ---------------------------------------------------------------------------
// Aggregate F=64 + softmax from fp16 H' (row = 128B; lane reads 2B).
// ---------------------------------------------------------------------------
__global__ __launch_bounds__(256) void k_agg64_softmax(const _Float16* __restrict__ H,
                                                       const int* __restrict__ row_ptr,
                                                       const int* __restrict__ csr,
                                                       const float* __restrict__ dis,
                                                       const float* __restrict__ bias,
                                                       float* __restrict__ out, int N) {
    int wave = threadIdx.x >> 6;
    int lane = threadIdx.x & 63;
    int node = blockIdx.x * 4 + wave;
    if (node >= N) return;
    int beg = row_ptr[node], end = row_ptr[node + 1];
    float acc = 0.f;

    int e = beg;
    for (; e + 8 <= end; e += 8) {
        int msrc = csr[e + (lane & 7)];
#pragma unroll
        for (int j = 0; j < 8; ++j) {
            int s = __shfl(msrc, j);
            acc += (float)H[(size_t)s * 64 + lane];
        }
    }
    if (e < end) {
        int idx = e + (lane & 7);
        int msrc = csr[idx < end ? idx : end - 1];
        int n = end - e;
#pragma unroll
        for (int j = 0; j < 8; ++j) {
            if (j < n) {
                int s = __shfl(msrc, j);
                acc += (float)H[(size_t)s * 64 + lane];
            }
        }
    }

    float di = dis[node];
    float v = fmaf(di, acc + (float)H[(size_t)node * 64 + lane], bias[lane]);
    float m = v;
#pragma unroll
    for (int off = 32; off; off >>= 1) m = fmaxf(m, __shfl_xor(m, off));
    float ex = __expf(v - m);
    float s = ex;
#pragma unroll
    for (int off = 32; off; off >>= 1) s += __shfl_xor(s, off);
    out[(size_t)node * 64 + lane] = ex / s;
}

// ---------------------------------------------------------------------------
extern "C" void kernel_launch(void* const* d_in, const int* in_sizes, int n_in,
                              void* d_out, int out_size, void* d_ws, size_t ws_size,
                              hipStream_t stream) {
    const float* x  = (const float*)d_in[0];
    const int*   ei = (const int*)d_in[1];
    const float* W0 = (const float*)d_in[2];
    const float* b0 = (const float*)d_in[3];
    const float* W1 = (const float*)d_in[4];
    const float* b1 = (const float*)d_in[5];
    const float* W2 = (const float*)d_in[6];
    const float* b2 = (const float*)d_in[7];
    const float* W3 = (const float*)d_in[8];
    const float* b3 = (const float*)d_in[9];

    const int N = in_sizes[0] / 512;   // 100000
    const int E = in_sizes[1] / 2;     // 3200000
    const int* src = ei;
    const int* dst = ei + E;

    auto align256 = [](size_t v) { return (v + 255) & ~(size_t)255; };
    char* w = (char*)d_ws;
    _Float16* hA = (_Float16*)w;     w += align256((size_t)N * 256 * 4);  // GEMM out H' (fp16)
    _Float16* hB = (_Float16*)w;     w += align256((size_t)N * 256 * 4);  // agg out (fp16)
    int*   csr = (int*)w;            w += align256((size_t)E * 4);
    int*   cnt = (int*)w;            w += align256((size_t)N * 4);
    float* dis = (float*)w;          w += align256((size_t)N * 4);
    int*   row_ptr = (int*)w;        w += align256((size_t)(N + 1) * 4);
    int*   fill_ptr = (int*)w;       w += align256((size_t)N * 4);
    int*   partials = (int*)w;       w += align256((size_t)1024 * 4);
    _Float16* Wt0 = (_Float16*)w;    w += align256((size_t)256 * 512 * 2);
    _Float16* Wt1 = (_Float16*)w;    w += align256((size_t)256 * 256 * 2);
    _Float16* Wt2 = (_Float16*)w;    w += align256((size_t)256 * 256 * 2);
    _Float16* Wt3 = (_Float16*)w;    w += align256((size_t)64 * 256 * 2);
    (void)ws_size; (void)n_in; (void)out_size;

    const int nchunks = (N + 1023) / 1024;

    hipMemsetAsync(cnt, 0, (size_t)N * 4, stream);
    k_degree<<<(E + 255) / 256, 256, 0, stream>>>(dst, cnt, E);
    k_dis<<<(N + 255) / 256, 256, 0, stream>>>(cnt, dis, N);
    k_scan1<<<nchunks, 1024, 0, stream>>>(cnt, row_ptr, partials, N);
    k_scan2<<<1, 1024, 0, stream>>>(partials, nchunks);
    k_scan3<<<(N + 1 + 255) / 256, 256, 0, stream>>>(row_ptr, partials, fill_ptr, N, E);
    k_fill<<<(E + 255) / 256, 256, 0, stream>>>(src, dst, fill_ptr, csr, E);

    k_convW<<<(512 * 256 + 255) / 256, 256, 0, stream>>>(W0, Wt0, 512, 256);
    k_convW<<<(256 * 256 + 255) / 256, 256, 0, stream>>>(W1, Wt1, 256, 256);
    k_convW<<<(256 * 256 + 255) / 256, 256, 0, stream>>>(W2, Wt2, 256, 256);
    k_convW<<<(256 * 64 + 255) / 256, 256, 0, stream>>>(W3, Wt3, 256, 64);

    const int gridM = (N + 127) / 128;
    const int nodeBlocks = (N + 3) / 4;

    // layer 0: x(f32) @ Wt0 -> hA fp16 ; agg -> hB fp16
    k_gemm_mfma<128, false, true><<<dim3(gridM, 2), 256, 0, stream>>>(x, Wt0, hA, dis,
                                                                      N, 512, 256);
    k_agg256_h<<<nodeBlocks, 256, 0, stream>>>((const float2*)hA, row_ptr, csr, dis, b0,
                                               hB, N);
    // layer 1
    k_gemm_mfma<128, true, true><<<dim3(gridM, 2), 256, 0, stream>>>(hB, Wt1, hA, dis,
                                                                     N, 256, 256);
    k_agg256_h<<<nodeBlocks, 256, 0, stream>>>((const float2*)hA, row_ptr, csr, dis, b1,
                                               hB, N);
    // layer 2
    k_gemm_mfma<128, true, true><<<dim3(gridM, 2), 256, 0, stream>>>(hB, Wt2, hA, dis,
                                                                     N, 256, 256);
    k_agg256_h<<<nodeBlocks, 256, 0, stream>>>((const float2*)hA, row_ptr, csr, dis, b2,
                                               hB, N);
    // layer 3: hB fp16 @ Wt3 -> hA fp16 (N x 64) ; agg + softmax -> d_out (f32)
    k_gemm_mfma<64, true, true><<<dim3(gridM, 1), 256, 0, stream>>>(hB, Wt3, hA, dis,
                                                                    N, 256, 64);
    k_agg64_softmax<<<nodeBlocks, 256, 0, stream>>>(hA, row_ptr, csr, dis, b3,
                                                    (float*)d_out, N);
}